// Round 1
// baseline (291.652 us; speedup 1.0000x reference)
//
#include <hip/hip_runtime.h>
#include <hip/hip_bf16.h>
#include <math.h>

// ---------------- problem constants ----------------
#define NB 4          // batch
#define LQ 1000       // queries
#define NHEAD 8
#define DHEAD 32
#define DMODEL 256
#define PSUM 64       // points per head (4 levels x 16)
#define STOT 19822    // total spatial size
#define IMGF 976.0f
#define GK 256        // K dim of all GEMMs

__device__ __constant__ int c_LH[4] = {122, 61, 31, 16};
__device__ __constant__ int c_LW[4] = {122, 61, 31, 16};
__device__ __constant__ int c_LST[4] = {0, 14884, 18605, 19566};

// ---------------- setup: per-batch constant matrices ----------------
// consts layout per n (stride 48 floats):
// [0..3] invA row-major, [4..5] t, [6..14] invA1 row-major, [15..17] b1,
// [18..29] P2 row-major 3x4, [30..31] ts, [32..37] T2 row-major 2x3
__global__ void setup_consts(const float* __restrict__ p_pfws,
                             const float* __restrict__ pt,
                             float* __restrict__ consts) {
    int n = threadIdx.x;
    if (n >= NB) return;
    const float* P1 = p_pfws + n * 12;
    const float* P2 = p_pfws + (n ^ 1) * 12;
    const float* T  = pt + n * 6;
    const float* T2 = pt + (n ^ 1) * 6;
    float* C = consts + n * 48;
    // 2x2 inverse of A=[[T0,T1],[T3,T4]], t=(T2,T5)
    float det = T[0]*T[4] - T[1]*T[3];
    float idet = 1.0f/det;
    C[0] =  T[4]*idet; C[1] = -T[1]*idet;
    C[2] = -T[3]*idet; C[3] =  T[0]*idet;
    C[4] = T[2]; C[5] = T[5];
    // 3x3 inverse of A1 (adjugate)
    float a=P1[0], b=P1[1], c=P1[2];
    float d=P1[4], e=P1[5], f=P1[6];
    float g=P1[8], h=P1[9], i=P1[10];
    float b10=P1[3], b11=P1[7], b12=P1[11];
    float A_=e*i-f*h, B_=c*h-b*i, Cc=b*f-c*e;
    float D_=f*g-d*i, E_=a*i-c*g, F_=c*d-a*f;
    float G_=d*h-e*g, H_=b*g-a*h, I_=a*e-b*d;
    float det3 = a*A_ + b*D_ + c*G_;
    float id3 = 1.0f/det3;
    C[6]=A_*id3;  C[7]=B_*id3;  C[8]=Cc*id3;
    C[9]=D_*id3;  C[10]=E_*id3; C[11]=F_*id3;
    C[12]=G_*id3; C[13]=H_*id3; C[14]=I_*id3;
    C[15]=b10; C[16]=b11; C[17]=b12;
    for (int k = 0; k < 12; ++k) C[18+k] = P2[k];
    // cam = -invA1 @ b1
    float cam0 = -(C[6]*b10  + C[7]*b11  + C[8]*b12);
    float cam1 = -(C[9]*b10  + C[10]*b11 + C[11]*b12);
    float cam2 = -(C[12]*b10 + C[13]*b11 + C[14]*b12);
    // ts = proj2(cam) with P2
    float y0 = P2[0]*cam0 + P2[1]*cam1 + P2[2]*cam2  + P2[3];
    float y1 = P2[4]*cam0 + P2[5]*cam1 + P2[6]*cam2  + P2[7];
    float y2 = P2[8]*cam0 + P2[9]*cam1 + P2[10]*cam2 + P2[11];
    float inv = 1.0f/(y2 + 1e-8f);
    C[30] = y0*inv; C[31] = y1*inv;
    for (int k = 0; k < 6; ++k) C[32+k] = T2[k];
}

// ---------------- generic fp32 GEMM: out[i,o] = X[i,:]·W[o,:] + bias[o] ----------------
// X: MxK row-major, W: NxK row-major, K = 256. BM=BN=64, BK=32, 256 threads, 4x4/thread.
__global__ __launch_bounds__(256)
void gemm_bias(const float* __restrict__ X, const float* __restrict__ W,
               const float* __restrict__ bias, float* __restrict__ out,
               int M, int N) {
    const int BM = 64, BN = 64, BK = 32;
    __shared__ float Xs[BK][BM + 4];   // [k][row] transposed for float4 reads
    __shared__ float Ws[BK][BN + 4];
    int i0 = blockIdx.x * BM;
    int o0 = blockIdx.y * BN;
    int tid = threadIdx.x;
    int ty = tid >> 4, tx = tid & 15;
    float acc[4][4] = {};
    int r  = tid >> 3;          // 0..31
    int kq = (tid & 7) * 4;     // 0..28
    for (int k0 = 0; k0 < GK; k0 += BK) {
        #pragma unroll
        for (int rr = r; rr < BM; rr += 32) {
            int gi = i0 + rr;
            float4 v = (gi < M) ? *(const float4*)(X + (size_t)gi*GK + k0 + kq)
                                : make_float4(0.f,0.f,0.f,0.f);
            Xs[kq+0][rr] = v.x; Xs[kq+1][rr] = v.y;
            Xs[kq+2][rr] = v.z; Xs[kq+3][rr] = v.w;
        }
        #pragma unroll
        for (int rr = r; rr < BN; rr += 32) {
            int go = o0 + rr;
            float4 v = *(const float4*)(W + (size_t)go*GK + k0 + kq);
            Ws[kq+0][rr] = v.x; Ws[kq+1][rr] = v.y;
            Ws[kq+2][rr] = v.z; Ws[kq+3][rr] = v.w;
        }
        __syncthreads();
        #pragma unroll
        for (int kk = 0; kk < BK; ++kk) {
            float4 av = *(const float4*)&Xs[kk][ty*4];
            float4 bv = *(const float4*)&Ws[kk][tx*4];
            float aa[4] = {av.x, av.y, av.z, av.w};
            float bb[4] = {bv.x, bv.y, bv.z, bv.w};
            #pragma unroll
            for (int ii = 0; ii < 4; ++ii)
                #pragma unroll
                for (int jj = 0; jj < 4; ++jj)
                    acc[ii][jj] += aa[ii] * bb[jj];
        }
        __syncthreads();
    }
    #pragma unroll
    for (int ii = 0; ii < 4; ++ii) {
        int gi = i0 + ty*4 + ii;
        if (gi < M) {
            #pragma unroll
            for (int jj = 0; jj < 4; ++jj) {
                int go = o0 + tx*4 + jj;
                out[(size_t)gi*N + go] = acc[ii][jj] + bias[go];
            }
        }
    }
}

// ---------------- fused: softmax + locations + bilinear sampling + weighted sum ----------------
// one block per (n,q); 256 threads = one output channel each (c = m*32+d)
__global__ __launch_bounds__(256)
void fused_sample(const float* __restrict__ logits,   // (4000, 512) m*64+p
                  const float* __restrict__ ref_pts,  // (4,1000,2)
                  const float* __restrict__ value,    // (4, 19822, 256)
                  const float* __restrict__ consts,   // 4*48
                  float* __restrict__ attn_out) {     // (4000, 256)
    int b = blockIdx.x;
    int n = b / LQ;
    int q = b - n * LQ;
    int tid = threadIdx.x;

    __shared__ float s_attn[512];
    __shared__ float s_loc[16][2];
    __shared__ int   s_idx[64][4];
    __shared__ float s_w[64][4];

    // load logits row
    s_attn[tid]       = logits[(size_t)b * 512 + tid];
    s_attn[tid + 256] = logits[(size_t)b * 512 + tid + 256];
    __syncthreads();

    // softmax per head (wave w handles heads w and w+4; wave64 shfl reduce)
    {
        int wave = tid >> 6, lane = tid & 63;
        for (int h = wave; h < NHEAD; h += 4) {
            float v = s_attn[h * 64 + lane];
            float mx = v;
            #pragma unroll
            for (int off = 32; off; off >>= 1) mx = fmaxf(mx, __shfl_xor(mx, off, 64));
            float e = expf(v - mx);
            float sm = e;
            #pragma unroll
            for (int off = 32; off; off >>= 1) sm += __shfl_xor(sm, off, 64);
            s_attn[h * 64 + lane] = e / sm;
        }
    }

    // sampling locations (16 distinct points, shared across the 4 levels)
    if (tid < 16) {
        const float* C = consts + n * 48;
        float rx = ref_pts[((size_t)n * LQ + q) * 2 + 0];
        float ry = ref_pts[((size_t)n * LQ + q) * 2 + 1];
        float dx = rx - C[4], dy = ry - C[5];
        float ox = (C[0]*dx + C[1]*dy) * IMGF;
        float oy = (C[2]*dx + C[3]*dy) * IMGF;
        float u0 = ox - C[15], u1 = oy - C[16], u2 = 1.0f - C[17];
        float r0 = C[6]*u0  + C[7]*u1  + C[8]*u2;
        float r1 = C[9]*u0  + C[10]*u1 + C[11]*u2;
        float r2 = C[12]*u0 + C[13]*u1 + C[14]*u2;
        float y0 = C[18]*r0 + C[19]*r1 + C[20]*r2 + C[21];
        float y1 = C[22]*r0 + C[23]*r1 + C[24]*r2 + C[25];
        float y2 = C[26]*r0 + C[27]*r1 + C[28]*r2 + C[29];
        float inv = 1.0f/(y2 + 1e-8f);
        float prx = y0*inv, pry = y1*inv;
        float ts0 = C[30], ts1 = C[31];
        float msx = (prx - ts0) / IMGF, msy = (pry - ts1) / IMGF;
        int j = tid;
        float xsj = IMGF * ((float)j / 15.0f);
        float lx = (ts0 + msx * xsj) / IMGF;
        float ly = (ts1 + msy * xsj) / IMGF;
        float Lx = C[32]*lx + C[33]*ly + C[34];
        float Ly = C[35]*lx + C[36]*ly + C[37];
        s_loc[j][0] = fminf(fmaxf(Lx, 0.0f), 1.0f);
        s_loc[j][1] = fminf(fmaxf(Ly, 0.0f), 1.0f);
    }
    __syncthreads();

    // per-point bilinear metadata (64 points: level = p>>4, sub-point = p&15)
    if (tid < 64) {
        int p = tid, lev = p >> 4, j = p & 15;
        int H = c_LH[lev], W = c_LW[lev], st = c_LST[lev];
        float gx = s_loc[j][0] * (float)W - 0.5f;
        float gy = s_loc[j][1] * (float)H - 0.5f;
        float x0f = floorf(gx), y0f = floorf(gy);
        float wx = gx - x0f, wy = gy - y0f;
        int x0 = (int)x0f, y0 = (int)y0f;
        int x1 = x0 + 1, y1 = y0 + 1;
        bool vx0 = (x0 >= 0) & (x0 < W), vx1 = (x1 >= 0) & (x1 < W);
        bool vy0 = (y0 >= 0) & (y0 < H), vy1 = (y1 >= 0) & (y1 < H);
        s_idx[p][0] = (vx0 & vy0) ? st + y0 * W + x0 : -1;  s_w[p][0] = (1.f-wx)*(1.f-wy);
        s_idx[p][1] = (vx1 & vy0) ? st + y0 * W + x1 : -1;  s_w[p][1] = wx*(1.f-wy);
        s_idx[p][2] = (vx0 & vy1) ? st + y1 * W + x0 : -1;  s_w[p][2] = (1.f-wx)*wy;
        s_idx[p][3] = (vx1 & vy1) ? st + y1 * W + x1 : -1;  s_w[p][3] = wx*wy;
    }
    __syncthreads();

    // gather + weighted sum; value batch is swap_pairs -> n^1
    const float* vbase = value + (size_t)(n ^ 1) * STOT * DMODEL;
    int m = tid >> 5;
    float acc = 0.0f;
    for (int p = 0; p < 64; ++p) {
        float wa = s_attn[m * 64 + p];
        float s = 0.0f;
        #pragma unroll
        for (int cc = 0; cc < 4; ++cc) {
            int idx = s_idx[p][cc];
            if (idx >= 0) s += s_w[p][cc] * vbase[(size_t)idx * DMODEL + tid];
        }
        acc += wa * s;
    }
    attn_out[(size_t)b * DMODEL + tid] = acc;
}

// ---------------- launch ----------------
extern "C" void kernel_launch(void* const* d_in, const int* in_sizes, int n_in,
                              void* d_out, int out_size, void* d_ws, size_t ws_size,
                              hipStream_t stream) {
    const float* query         = (const float*)d_in[0];
    const float* input_flatten = (const float*)d_in[1];
    const float* ref_pts       = (const float*)d_in[2];
    const float* p_pfws        = (const float*)d_in[3];
    const float* pt            = (const float*)d_in[4];
    const float* W_val         = (const float*)d_in[5];
    const float* b_val         = (const float*)d_in[6];
    const float* W_attn        = (const float*)d_in[7];
    const float* b_attn        = (const float*)d_in[8];
    const float* W_out         = (const float*)d_in[9];
    const float* b_out         = (const float*)d_in[10];
    float* out = (float*)d_out;
    float* ws  = (float*)d_ws;

    const size_t n_value  = (size_t)NB * STOT * DMODEL;        // 20,297,728
    const size_t n_logits = (size_t)NB * LQ * 512;             //  2,048,000
    const size_t n_attnout= (size_t)NB * LQ * DMODEL;          //  1,024,000
    const size_t n_consts = NB * 48;
    const size_t need_bytes = (n_value + n_logits + n_attnout + n_consts) * sizeof(float);
    if (ws_size < need_bytes) return;   // visible failure instead of corruption

    float* value    = ws;
    float* logits   = value + n_value;
    float* attn_out = logits + n_logits;
    float* consts   = attn_out + n_attnout;

    setup_consts<<<1, 64, 0, stream>>>(p_pfws, pt, consts);

    {   // value = input_flatten @ W_val.T + b_val
        dim3 g((NB * STOT + 63) / 64, DMODEL / 64);
        gemm_bias<<<g, 256, 0, stream>>>(input_flatten, W_val, b_val, value, NB * STOT, DMODEL);
    }
    {   // logits = query @ W_attn.T + b_attn
        dim3 g((NB * LQ + 63) / 64, 512 / 64);
        gemm_bias<<<g, 256, 0, stream>>>(query, W_attn, b_attn, logits, NB * LQ, 512);
    }
    fused_sample<<<NB * LQ, 256, 0, stream>>>(logits, ref_pts, value, consts, attn_out);
    {   // out = attn_out @ W_out.T + b_out
        dim3 g((NB * LQ + 63) / 64, DMODEL / 64);
        gemm_bias<<<g, 256, 0, stream>>>(attn_out, W_out, b_out, out, NB * LQ, DMODEL);
    }
}